// Round 8
// baseline (71.505 us; speedup 1.0000x reference)
//
#include <hip/hip_runtime.h>
#include <math.h>

#define BB 32
#define TT 8192
#define CCH 128
#define OO 64
#define DD 288
#define NFREQ 12
#define NIJ 144

typedef _Float16 v8h __attribute__((ext_vector_type(8)));
typedef float f32x4 __attribute__((ext_vector_type(4)));

// ---------------- K0: transpose heads [64][288] -> Ht [288][64] ----------------
__global__ __launch_bounds__(256) void k0_transpose_heads(const float* __restrict__ heads,
                                                          float* __restrict__ Ht) {
    int idx = blockIdx.x * 256 + threadIdx.x;
    if (idx < OO * DD) {
        int o = idx / DD;
        int d = idx - o * DD;
        Ht[d * OO + o] = heads[idx];
    }
}

// ---------------- K1: fourier emb + scores + softmax -> w [B][O][C] ----------------
#define IJ_CHUNK 36
#define EMB_LD 129

__global__ __launch_bounds__(256) void k1_weights(const float* __restrict__ pos,
                                                  const float* __restrict__ Ht,
                                                  float* __restrict__ w) {
    __shared__ float smem[2 * IJ_CHUNK * EMB_LD];   // 9288 floats = 37 KB
    float* cos_s = smem;
    float* sin_s = smem + IJ_CHUNK * EMB_LD;

    const int b = blockIdx.x;
    const int obase = blockIdx.y * 16;
    const int tid = threadIdx.x;
    const int c = tid & 127;
    const int hh = __builtin_amdgcn_readfirstlane(tid >> 7);  // wave-uniform

    const float* posb = pos + b * CCH * 2;
    const float S = 4.487989505128276f;  // 2*pi/1.4

    float accs[8];
#pragma unroll
    for (int k = 0; k < 8; ++k) accs[k] = 0.f;

#pragma unroll 1
    for (int cc = 0; cc < NIJ; cc += IJ_CHUNK) {
#pragma unroll 1
        for (int it = 0; it < (IJ_CHUNK * CCH) / 256; ++it) {
            int idx = it * 256 + tid;
            int ec = idx & 127;
            int ijl = idx >> 7;
            int ij = cc + ijl;
            int i = ij / NFREQ;
            int j = ij - i * NFREQ;
            float px = posb[2 * ec] + 0.2f;
            float py = posb[2 * ec + 1] + 0.2f;
            float ang = px * (S * (float)i) + py * (S * (float)j);
            float sv, cv;
            __sincosf(ang, &sv, &cv);
            cos_s[ijl * EMB_LD + ec] = cv;
            sin_s[ijl * EMB_LD + ec] = sv;
        }
        __syncthreads();
#pragma unroll 4
        for (int ijl = 0; ijl < IJ_CHUNK; ++ijl) {
            float cv = cos_s[ijl * EMB_LD + c];
            float sv = sin_s[ijl * EMB_LD + c];
            const float* hc = Ht + (cc + ijl) * OO + obase + hh * 8;
            const float* hs = Ht + (NIJ + cc + ijl) * OO + obase + hh * 8;
#pragma unroll
            for (int k = 0; k < 8; ++k) {
                accs[k] = fmaf(cv, hc[k], fmaf(sv, hs[k], accs[k]));
            }
        }
        __syncthreads();
    }

    // scores -> LDS [16][129]
    float* sc = smem;
#pragma unroll
    for (int k = 0; k < 8; ++k) {
        sc[(hh * 8 + k) * EMB_LD + c] = accs[k];
    }
    __syncthreads();

    // parallel softmax: o16 = tid>>4 owns one o-row; part = tid&15 owns 8 channels
    float* red  = smem + 16 * EMB_LD;        // 256 floats
    float* red2 = red + 256;                 // 256 floats
    const int o16 = tid >> 4;
    const int part = tid & 15;
    const float* srow = sc + o16 * EMB_LD + part * 8;

    float m = -1e30f;
#pragma unroll
    for (int j = 0; j < 8; ++j) m = fmaxf(m, srow[j]);
    red[o16 * 16 + part] = m;
    __syncthreads();
    float M = red[o16 * 16];
#pragma unroll
    for (int p = 1; p < 16; ++p) M = fmaxf(M, red[o16 * 16 + p]);

    float ev[8];
    float s = 0.f;
#pragma unroll
    for (int j = 0; j < 8; ++j) { ev[j] = __expf(srow[j] - M); s += ev[j]; }
    red2[o16 * 16 + part] = s;
    __syncthreads();
    float Sum = 0.f;
#pragma unroll
    for (int p = 0; p < 16; ++p) Sum += red2[o16 * 16 + p];
    float inv = 1.f / Sum;

    float* wrow = w + ((size_t)(b * OO + obase + o16)) * CCH + part * 8;
#pragma unroll
    for (int j = 0; j < 8; ++j) wrow[j] = ev[j] * inv;
}

// ---------------- K1b: pack weights into fp16 MFMA fragments ----------------
// A-operand of mfma_f32_16x16x32_f16: lane holds W[row=o][8 k-elems],
// row = lane&15 within ot tile, k = (lane>>4)*8 + i. Same per-lane k-order as
// the eeg fragment in k2, so any internal k-permutation cancels.
// frag index: (((b*4 + kc)*4 + ot)*64 + lane), 16B per lane.
__global__ __launch_bounds__(256) void k1b_frag(const float* __restrict__ w,
                                                uint4* __restrict__ fragH) {
    const int b = blockIdx.x;
    const int kc = blockIdx.y;
    const int ot = threadIdx.x >> 6;
    const int lane = threadIdx.x & 63;
    const int o = ot * 16 + (lane & 15);
    const int cbase = kc * 32 + (lane >> 4) * 8;
    const float* wrow = w + ((size_t)(b * OO + o)) * CCH + cbase;

    float4 a = *(const float4*)wrow;
    float4 c = *(const float4*)(wrow + 4);
    v8h h;
    h[0] = (_Float16)a.x; h[1] = (_Float16)a.y;
    h[2] = (_Float16)a.z; h[3] = (_Float16)a.w;
    h[4] = (_Float16)c.x; h[5] = (_Float16)c.y;
    h[6] = (_Float16)c.z; h[7] = (_Float16)c.w;

    union { uint4 u; v8h v; } u;
    u.v = h;
    fragH[((b * 4 + kc) * 4 + ot) * 64 + lane] = u.u;
}

// ---------------- K2: out[b,t,o] = sum_c eeg[b,t,c] * w[b,o,c] via fp16 MFMA ----
// TLP restructure (R7->R8): wave owns 2 t-tiles (32 rows) instead of 4 ->
// acc 32 + bw 16 + loads 16 + eh 8 + addr ~12 = ~95 VGPR -> ~5 waves/SIMD
// (vs ~140 VGPR / 3 waves before). Block = 4 waves = 128 t-rows; grid (64, 32).
// mfma(A=w_frag, B=eeg_frag): D[row=o_local=kq*4+reg][col=t_local=r16] ->
// float4 stores. RULE #20: every acc[][] loop fully unrolled.
__global__ __launch_bounds__(256) void k2_mfma(const float* __restrict__ eeg,
                                               const uint4* __restrict__ fragH,
                                               float* __restrict__ out) {
    const int b = blockIdx.y;
    const int t0 = blockIdx.x * 128;
    const int lane = threadIdx.x & 63;
    const int wv = __builtin_amdgcn_readfirstlane(threadIdx.x >> 6);
    const int r16 = lane & 15;
    const int kq = lane >> 4;

    const float* ebase = eeg + ((size_t)b * TT + t0 + wv * 32) * CCH;

    f32x4 acc[2][4];
#pragma unroll
    for (int tt = 0; tt < 2; ++tt)
#pragma unroll
        for (int ot = 0; ot < 4; ++ot)
            acc[tt][ot] = (f32x4){0.f, 0.f, 0.f, 0.f};

#pragma unroll 1
    for (int kc = 0; kc < 4; ++kc) {
        const uint4* fh = fragH + (size_t)((b * 4 + kc) * 4) * 64 + lane;
        v8h bw[4];
#pragma unroll
        for (int ot = 0; ot < 4; ++ot) {
            union { uint4 u; v8h v; } u;
            u.u = fh[ot * 64];
            bw[ot] = u.v;
        }
#pragma unroll
        for (int tt = 0; tt < 2; ++tt) {
            const float* ap = ebase + (size_t)(tt * 16 + r16) * CCH + kc * 32 + kq * 8;
            float4 v0 = *(const float4*)ap;
            float4 v1 = *(const float4*)(ap + 4);
            v8h eh;
            eh[0] = (_Float16)v0.x; eh[1] = (_Float16)v0.y;
            eh[2] = (_Float16)v0.z; eh[3] = (_Float16)v0.w;
            eh[4] = (_Float16)v1.x; eh[5] = (_Float16)v1.y;
            eh[6] = (_Float16)v1.z; eh[7] = (_Float16)v1.w;
#pragma unroll
            for (int ot = 0; ot < 4; ++ot) {
                acc[tt][ot] = __builtin_amdgcn_mfma_f32_16x16x32_f16(bw[ot], eh, acc[tt][ot], 0, 0, 0);
            }
        }
    }

    // epilogue: lane holds D[o_local = kq*4 + reg][t_local = r16] per (tt,ot)
    const size_t orow0 = (size_t)b * TT + t0 + wv * 32;
#pragma unroll
    for (int tt = 0; tt < 2; ++tt) {
        float* dst_row = out + (orow0 + tt * 16 + r16) * OO + kq * 4;
#pragma unroll
        for (int ot = 0; ot < 4; ++ot) {
            float4 v;
            v.x = acc[tt][ot][0];
            v.y = acc[tt][ot][1];
            v.z = acc[tt][ot][2];
            v.w = acc[tt][ot][3];
            *(float4*)(dst_row + ot * 16) = v;
        }
    }
}

extern "C" void kernel_launch(void* const* d_in, const int* in_sizes, int n_in,
                              void* d_out, int out_size, void* d_ws, size_t ws_size,
                              hipStream_t stream) {
    const float* eeg   = (const float*)d_in[0];   // [B,T,C]
    const float* pos   = (const float*)d_in[1];   // [B,C,2]
    const float* heads = (const float*)d_in[2];   // [O,D]
    float* out = (float*)d_out;                   // [B,T,O]

    char* ws = (char*)d_ws;
    float* Ht     = (float*)ws;                       // 288*64*4    = 73728 B
    float* w      = (float*)(ws + 73728);             // 32*64*128*4 = 1048576 B
    uint4* fragH  = (uint4*)(ws + 73728 + 1048576);   // 32*4*4*64*16 = 524288 B

    k0_transpose_heads<<<(OO * DD + 255) / 256, 256, 0, stream>>>(heads, Ht);
    k1_weights<<<dim3(BB, 4), 256, 0, stream>>>(pos, Ht, w);
    k1b_frag<<<dim3(BB, 4), 256, 0, stream>>>(w, fragH);
    k2_mfma<<<dim3(TT / 128, BB), 256, 0, stream>>>(eeg, fragH, out);
}

// Round 9
// 71.400 us; speedup vs baseline: 1.0015x; 1.0015x over previous
//
#include <hip/hip_runtime.h>
#include <math.h>

#define BB 32
#define TT 8192
#define CCH 128
#define OO 64
#define DD 288
#define NFREQ 12
#define NIJ 144

typedef _Float16 v8h __attribute__((ext_vector_type(8)));
typedef float f32x4 __attribute__((ext_vector_type(4)));

// ---------------- K0: transpose heads [64][288] -> Ht [288][64] ----------------
__global__ __launch_bounds__(256) void k0_transpose_heads(const float* __restrict__ heads,
                                                          float* __restrict__ Ht) {
    int idx = blockIdx.x * 256 + threadIdx.x;
    if (idx < OO * DD) {
        int o = idx / DD;
        int d = idx - o * DD;
        Ht[d * OO + o] = heads[idx];
    }
}

// ---------------- K1: fourier emb + scores + softmax -> w [B][O][C] ----------------
#define IJ_CHUNK 36
#define EMB_LD 129

__global__ __launch_bounds__(256) void k1_weights(const float* __restrict__ pos,
                                                  const float* __restrict__ Ht,
                                                  float* __restrict__ w) {
    __shared__ float smem[2 * IJ_CHUNK * EMB_LD];   // 9288 floats = 37 KB
    float* cos_s = smem;
    float* sin_s = smem + IJ_CHUNK * EMB_LD;

    const int b = blockIdx.x;
    const int obase = blockIdx.y * 16;
    const int tid = threadIdx.x;
    const int c = tid & 127;
    const int hh = __builtin_amdgcn_readfirstlane(tid >> 7);  // wave-uniform

    const float* posb = pos + b * CCH * 2;
    const float S = 4.487989505128276f;  // 2*pi/1.4

    float accs[8];
#pragma unroll
    for (int k = 0; k < 8; ++k) accs[k] = 0.f;

#pragma unroll 1
    for (int cc = 0; cc < NIJ; cc += IJ_CHUNK) {
#pragma unroll 1
        for (int it = 0; it < (IJ_CHUNK * CCH) / 256; ++it) {
            int idx = it * 256 + tid;
            int ec = idx & 127;
            int ijl = idx >> 7;
            int ij = cc + ijl;
            int i = ij / NFREQ;
            int j = ij - i * NFREQ;
            float px = posb[2 * ec] + 0.2f;
            float py = posb[2 * ec + 1] + 0.2f;
            float ang = px * (S * (float)i) + py * (S * (float)j);
            float sv, cv;
            __sincosf(ang, &sv, &cv);
            cos_s[ijl * EMB_LD + ec] = cv;
            sin_s[ijl * EMB_LD + ec] = sv;
        }
        __syncthreads();
#pragma unroll 4
        for (int ijl = 0; ijl < IJ_CHUNK; ++ijl) {
            float cv = cos_s[ijl * EMB_LD + c];
            float sv = sin_s[ijl * EMB_LD + c];
            const float* hc = Ht + (cc + ijl) * OO + obase + hh * 8;
            const float* hs = Ht + (NIJ + cc + ijl) * OO + obase + hh * 8;
#pragma unroll
            for (int k = 0; k < 8; ++k) {
                accs[k] = fmaf(cv, hc[k], fmaf(sv, hs[k], accs[k]));
            }
        }
        __syncthreads();
    }

    // scores -> LDS [16][129]
    float* sc = smem;
#pragma unroll
    for (int k = 0; k < 8; ++k) {
        sc[(hh * 8 + k) * EMB_LD + c] = accs[k];
    }
    __syncthreads();

    // parallel softmax: o16 = tid>>4 owns one o-row; part = tid&15 owns 8 channels
    float* red  = smem + 16 * EMB_LD;        // 256 floats
    float* red2 = red + 256;                 // 256 floats
    const int o16 = tid >> 4;
    const int part = tid & 15;
    const float* srow = sc + o16 * EMB_LD + part * 8;

    float m = -1e30f;
#pragma unroll
    for (int j = 0; j < 8; ++j) m = fmaxf(m, srow[j]);
    red[o16 * 16 + part] = m;
    __syncthreads();
    float M = red[o16 * 16];
#pragma unroll
    for (int p = 1; p < 16; ++p) M = fmaxf(M, red[o16 * 16 + p]);

    float ev[8];
    float s = 0.f;
#pragma unroll
    for (int j = 0; j < 8; ++j) { ev[j] = __expf(srow[j] - M); s += ev[j]; }
    red2[o16 * 16 + part] = s;
    __syncthreads();
    float Sum = 0.f;
#pragma unroll
    for (int p = 0; p < 16; ++p) Sum += red2[o16 * 16 + p];
    float inv = 1.f / Sum;

    float* wrow = w + ((size_t)(b * OO + obase + o16)) * CCH + part * 8;
#pragma unroll
    for (int j = 0; j < 8; ++j) wrow[j] = ev[j] * inv;
}

// ---------------- K1b: pack weights into fp16 MFMA fragments ----------------
// A-operand of mfma_f32_16x16x32_f16: lane holds W[row=o][8 k-elems],
// row = lane&15 within ot tile, k = (lane>>4)*8 + i. Same per-lane k-order as
// the eeg fragment in k2 (LDS read at halves [kc*32 + q*8 .. +8)), so any
// internal k-permutation cancels.
__global__ __launch_bounds__(256) void k1b_frag(const float* __restrict__ w,
                                                uint4* __restrict__ fragH) {
    const int b = blockIdx.x;
    const int kc = blockIdx.y;
    const int ot = threadIdx.x >> 6;
    const int lane = threadIdx.x & 63;
    const int o = ot * 16 + (lane & 15);
    const int cbase = kc * 32 + (lane >> 4) * 8;
    const float* wrow = w + ((size_t)(b * OO + o)) * CCH + cbase;

    float4 a = *(const float4*)wrow;
    float4 c = *(const float4*)(wrow + 4);
    v8h h;
    h[0] = (_Float16)a.x; h[1] = (_Float16)a.y;
    h[2] = (_Float16)a.z; h[3] = (_Float16)a.w;
    h[4] = (_Float16)c.x; h[5] = (_Float16)c.y;
    h[6] = (_Float16)c.z; h[7] = (_Float16)c.w;

    union { uint4 u; v8h v; } u;
    u.v = h;
    fragH[((b * 4 + kc) * 4 + ot) * 64 + lane] = u.u;
}

// ---------------- K2: out[b,t,o] = sum_c eeg[b,t,c] * w[b,o,c] via fp16 MFMA ----
// LDS-staged (R8->R9): the MFMA fragment layout forced each eeg load to scatter
// 64 lanes over 16 rows x 512B stride (the G2 anti-pattern; ~52% BW eff).
// Now: wave stages its 32 rows x 512B (16KB contiguous) with per-lane CONTIGUOUS
// 32B loads (lane l -> byte 32*l of each 2KB step - copy-ubench pattern),
// converts fp32->fp16 (RNE) in regs, ds_write_b128 to padded fp16 tile [32][136]
// (272B rows, 16B aligned). Fragments then come from ds_read_b128 (~8-way bank
// alias, ~36% LDS duty - off the critical path). cvt leaves the inner loop.
// RULE #20: all acc[][] loops fully unrolled.
#define LDSH 136   // halves per row (128 data + 8 pad)

__global__ __launch_bounds__(256) void k2_mfma(const float* __restrict__ eeg,
                                               const uint4* __restrict__ fragH,
                                               float* __restrict__ out) {
    __shared__ _Float16 lds[4 * 32 * LDSH];   // 34816 B
    const int b = blockIdx.y;
    const int t0 = blockIdx.x * 128;
    const int lane = threadIdx.x & 63;
    const int wv = __builtin_amdgcn_readfirstlane(threadIdx.x >> 6);
    const int r16 = lane & 15;
    const int q = lane >> 4;

    _Float16* lw = lds + wv * 32 * LDSH;
    const float* slice = eeg + ((size_t)b * TT + t0 + wv * 32) * CCH;  // 16 KB

    // ---- stage: 8 steps; lane loads 32B contiguous; cvt; one ds_write_b128 ----
#pragma unroll
    for (int p = 0; p < 8; ++p) {
        const float* src = slice + (size_t)(p * 64 + lane) * 8;   // bytes 32*(p*64+lane)
        float4 v0 = *(const float4*)src;
        float4 v1 = *(const float4*)(src + 4);
        v8h h;
        h[0] = (_Float16)v0.x; h[1] = (_Float16)v0.y;
        h[2] = (_Float16)v0.z; h[3] = (_Float16)v0.w;
        h[4] = (_Float16)v1.x; h[5] = (_Float16)v1.y;
        h[6] = (_Float16)v1.z; h[7] = (_Float16)v1.w;
        int G = p * 64 + lane;          // fp16 16B-granule index in wave tile
        int row = G >> 4;               // 16 granules per 256B row
        int cg = G & 15;
        *(v8h*)(lw + row * LDSH + cg * 8) = h;
    }
    __syncthreads();

    // ---- consume: fragments from LDS, fp16 MFMA ----
    f32x4 acc[2][4];
#pragma unroll
    for (int tt = 0; tt < 2; ++tt)
#pragma unroll
        for (int ot = 0; ot < 4; ++ot)
            acc[tt][ot] = (f32x4){0.f, 0.f, 0.f, 0.f};

#pragma unroll
    for (int kc = 0; kc < 4; ++kc) {
        const uint4* fh = fragH + (size_t)((b * 4 + kc) * 4) * 64 + lane;
        v8h bw[4];
#pragma unroll
        for (int ot = 0; ot < 4; ++ot) {
            union { uint4 u; v8h v; } u;
            u.u = fh[ot * 64];
            bw[ot] = u.v;
        }
#pragma unroll
        for (int tt = 0; tt < 2; ++tt) {
            // lane reads eeg[row = tt*16+r16][halves kc*32 + q*8 .. +8)
            v8h eh = *(const v8h*)(lw + (tt * 16 + r16) * LDSH + (kc * 4 + q) * 8);
#pragma unroll
            for (int ot = 0; ot < 4; ++ot) {
                acc[tt][ot] = __builtin_amdgcn_mfma_f32_16x16x32_f16(bw[ot], eh, acc[tt][ot], 0, 0, 0);
            }
        }
    }

    // epilogue: lane holds D[o_local = q*4 + reg][t_local = r16] per (tt,ot)
    const size_t orow0 = (size_t)b * TT + t0 + wv * 32;
#pragma unroll
    for (int tt = 0; tt < 2; ++tt) {
        float* dst_row = out + (orow0 + tt * 16 + r16) * OO + q * 4;
#pragma unroll
        for (int ot = 0; ot < 4; ++ot) {
            float4 v;
            v.x = acc[tt][ot][0];
            v.y = acc[tt][ot][1];
            v.z = acc[tt][ot][2];
            v.w = acc[tt][ot][3];
            *(float4*)(dst_row + ot * 16) = v;
        }
    }
}

extern "C" void kernel_launch(void* const* d_in, const int* in_sizes, int n_in,
                              void* d_out, int out_size, void* d_ws, size_t ws_size,
                              hipStream_t stream) {
    const float* eeg   = (const float*)d_in[0];   // [B,T,C]
    const float* pos   = (const float*)d_in[1];   // [B,C,2]
    const float* heads = (const float*)d_in[2];   // [O,D]
    float* out = (float*)d_out;                   // [B,T,O]

    char* ws = (char*)d_ws;
    float* Ht     = (float*)ws;                       // 288*64*4    = 73728 B
    float* w      = (float*)(ws + 73728);             // 32*64*128*4 = 1048576 B
    uint4* fragH  = (uint4*)(ws + 73728 + 1048576);   // 32*4*4*64*16 = 524288 B

    k0_transpose_heads<<<(OO * DD + 255) / 256, 256, 0, stream>>>(heads, Ht);
    k1_weights<<<dim3(BB, 4), 256, 0, stream>>>(pos, Ht, w);
    k1b_frag<<<dim3(BB, 4), 256, 0, stream>>>(w, fragH);
    k2_mfma<<<dim3(TT / 128, BB), 256, 0, stream>>>(eeg, fragH, out);
}

// Round 10
// 69.665 us; speedup vs baseline: 1.0264x; 1.0249x over previous
//
#include <hip/hip_runtime.h>
#include <math.h>

#define BB 32
#define TT 8192
#define CCH 128
#define OO 64
#define DD 288
#define NFREQ 12
#define NIJ 144

typedef _Float16 v8h __attribute__((ext_vector_type(8)));
typedef float f32x4 __attribute__((ext_vector_type(4)));

// ---------------- K0: transpose heads [64][288] -> Ht [288][64] ----------------
__global__ __launch_bounds__(256) void k0_transpose_heads(const float* __restrict__ heads,
                                                          float* __restrict__ Ht) {
    int idx = blockIdx.x * 256 + threadIdx.x;
    if (idx < OO * DD) {
        int o = idx / DD;
        int d = idx - o * DD;
        Ht[d * OO + o] = heads[idx];
    }
}

// ---------------- K1: fourier emb + scores + softmax -> w [B][O][C] ----------------
#define IJ_CHUNK 36
#define EMB_LD 129

__global__ __launch_bounds__(256) void k1_weights(const float* __restrict__ pos,
                                                  const float* __restrict__ Ht,
                                                  float* __restrict__ w) {
    __shared__ float smem[2 * IJ_CHUNK * EMB_LD];   // 9288 floats = 37 KB
    float* cos_s = smem;
    float* sin_s = smem + IJ_CHUNK * EMB_LD;

    const int b = blockIdx.x;
    const int obase = blockIdx.y * 16;
    const int tid = threadIdx.x;
    const int c = tid & 127;
    const int hh = __builtin_amdgcn_readfirstlane(tid >> 7);  // wave-uniform

    const float* posb = pos + b * CCH * 2;
    const float S = 4.487989505128276f;  // 2*pi/1.4

    float accs[8];
#pragma unroll
    for (int k = 0; k < 8; ++k) accs[k] = 0.f;

#pragma unroll 1
    for (int cc = 0; cc < NIJ; cc += IJ_CHUNK) {
#pragma unroll 1
        for (int it = 0; it < (IJ_CHUNK * CCH) / 256; ++it) {
            int idx = it * 256 + tid;
            int ec = idx & 127;
            int ijl = idx >> 7;
            int ij = cc + ijl;
            int i = ij / NFREQ;
            int j = ij - i * NFREQ;
            float px = posb[2 * ec] + 0.2f;
            float py = posb[2 * ec + 1] + 0.2f;
            float ang = px * (S * (float)i) + py * (S * (float)j);
            float sv, cv;
            __sincosf(ang, &sv, &cv);
            cos_s[ijl * EMB_LD + ec] = cv;
            sin_s[ijl * EMB_LD + ec] = sv;
        }
        __syncthreads();
#pragma unroll 4
        for (int ijl = 0; ijl < IJ_CHUNK; ++ijl) {
            float cv = cos_s[ijl * EMB_LD + c];
            float sv = sin_s[ijl * EMB_LD + c];
            const float* hc = Ht + (cc + ijl) * OO + obase + hh * 8;
            const float* hs = Ht + (NIJ + cc + ijl) * OO + obase + hh * 8;
#pragma unroll
            for (int k = 0; k < 8; ++k) {
                accs[k] = fmaf(cv, hc[k], fmaf(sv, hs[k], accs[k]));
            }
        }
        __syncthreads();
    }

    // scores -> LDS [16][129]
    float* sc = smem;
#pragma unroll
    for (int k = 0; k < 8; ++k) {
        sc[(hh * 8 + k) * EMB_LD + c] = accs[k];
    }
    __syncthreads();

    // parallel softmax: o16 = tid>>4 owns one o-row; part = tid&15 owns 8 channels
    float* red  = smem + 16 * EMB_LD;        // 256 floats
    float* red2 = red + 256;                 // 256 floats
    const int o16 = tid >> 4;
    const int part = tid & 15;
    const float* srow = sc + o16 * EMB_LD + part * 8;

    float m = -1e30f;
#pragma unroll
    for (int j = 0; j < 8; ++j) m = fmaxf(m, srow[j]);
    red[o16 * 16 + part] = m;
    __syncthreads();
    float M = red[o16 * 16];
#pragma unroll
    for (int p = 1; p < 16; ++p) M = fmaxf(M, red[o16 * 16 + p]);

    float ev[8];
    float s = 0.f;
#pragma unroll
    for (int j = 0; j < 8; ++j) { ev[j] = __expf(srow[j] - M); s += ev[j]; }
    red2[o16 * 16 + part] = s;
    __syncthreads();
    float Sum = 0.f;
#pragma unroll
    for (int p = 0; p < 16; ++p) Sum += red2[o16 * 16 + p];
    float inv = 1.f / Sum;

    float* wrow = w + ((size_t)(b * OO + obase + o16)) * CCH + part * 8;
#pragma unroll
    for (int j = 0; j < 8; ++j) wrow[j] = ev[j] * inv;
}

// ---------------- K1b: pack weights into fp16 MFMA fragments ----------------
// A-operand of mfma_f32_16x16x32_f16: lane holds W[row=o][8 k-elems],
// row = lane&15 within ot tile, k = (lane>>4)*8 + i. Same per-lane k-order as
// the eeg fragment in k2, so any internal k-permutation cancels.
__global__ __launch_bounds__(256) void k1b_frag(const float* __restrict__ w,
                                                uint4* __restrict__ fragH) {
    const int b = blockIdx.x;
    const int kc = blockIdx.y;
    const int ot = threadIdx.x >> 6;
    const int lane = threadIdx.x & 63;
    const int o = ot * 16 + (lane & 15);
    const int cbase = kc * 32 + (lane >> 4) * 8;
    const float* wrow = w + ((size_t)(b * OO + o)) * CCH + cbase;

    float4 a = *(const float4*)wrow;
    float4 c = *(const float4*)(wrow + 4);
    v8h h;
    h[0] = (_Float16)a.x; h[1] = (_Float16)a.y;
    h[2] = (_Float16)a.z; h[3] = (_Float16)a.w;
    h[4] = (_Float16)c.x; h[5] = (_Float16)c.y;
    h[6] = (_Float16)c.z; h[7] = (_Float16)c.w;

    union { uint4 u; v8h v; } u;
    u.v = h;
    fragH[((b * 4 + kc) * 4 + ot) * 64 + lane] = u.u;
}

// ---------------- K2: persistent-wave pipelined MFMA merge ----------------
// 512 blocks x 4 waves = 2048 waves; wave owns 128 t-rows of one b (8 tiles of
// 16 rows). Per iteration: DMA next tile HBM->LDS via 8x global_load_lds(16B)
// (wave-uniform LDS dest, per-lane PRE-SWIZZLED global src: granule ^= row&7,
// rule #21 involution), s_waitcnt vmcnt(8) — the 8 new loads STAY IN FLIGHT
// (T4: never vmcnt(0) in the loop) — then consume current tile from LDS
// (ds_read_b128 conflict-optimal thanks to swizzle), cvt fp32->fp16, 16 MFMA,
// 4 float4 stores. W-fragments: 64 VGPR, loaded once (L2-hot). No barriers:
// waves fully independent (private 16 KB LDS each). RULE #20: acc static.
__device__ __forceinline__ void load_lds16(const float* g, float* l) {
    __builtin_amdgcn_global_load_lds(
        (const __attribute__((address_space(1))) unsigned int*)g,
        (__attribute__((address_space(3))) unsigned int*)l,
        16, 0, 0);
}

__global__ __launch_bounds__(256) void k2_mfma(const float* __restrict__ eeg,
                                               const uint4* __restrict__ fragH,
                                               float* __restrict__ out) {
    __shared__ float lds[4][2][2048];   // per wave: 2 bufs x (16 rows x 128 fp32) = 16 KB
    const int lane = threadIdx.x & 63;
    const int wv = __builtin_amdgcn_readfirstlane(threadIdx.x >> 6);
    const int wgid = blockIdx.x * 4 + wv;
    const int b = wgid >> 6;        // 64 waves per b
    const int chunk = wgid & 63;    // 128-row chunk within b
    const int r16 = lane & 15;
    const int q = lane >> 4;

    // ---- load the 16 w-fragments for this b (64 VGPR, stays live) ----
    v8h bw[4][4];
    {
        const uint4* fp = fragH + (size_t)(b * 16) * 64 + lane;
#pragma unroll
        for (int kc = 0; kc < 4; ++kc)
#pragma unroll
            for (int ot = 0; ot < 4; ++ot) {
                union { uint4 u; v8h v; } u;
                u.u = fp[(kc * 4 + ot) * 64];
                bw[kc][ot] = u.v;
            }
    }

    const float* slice = eeg + ((size_t)b * TT + chunk * 128) * CCH;  // 64 KB
    const size_t orow_base = (size_t)b * TT + chunk * 128;

    // stage tile -> buf: 8 x 1KB DMA steps; source granule pre-swizzled
#define STAGE(tile, buf)                                                        \
    {                                                                           \
        const float* tsrc = slice + (size_t)(tile) * 16 * CCH;                  \
        float* dst = &lds[wv][buf][0];                                          \
        _Pragma("unroll")                                                       \
        for (int s = 0; s < 8; ++s) {                                           \
            int G = s * 64 + lane;      /* 16B-granule idx in 8KB tile */       \
            int r = G >> 5;             /* row 0..15 */                         \
            int g = G & 31;             /* granule within 512B row */           \
            int gs = g ^ (r & 7);       /* pre-swizzled source granule */       \
            load_lds16(tsrc + r * CCH + gs * 4, dst + s * 256);                 \
        }                                                                       \
    }

#define CONSUME(tile, buf)                                                      \
    {                                                                           \
        const float* lbase = &lds[wv][buf][0];                                  \
        f32x4 acc[4];                                                           \
        _Pragma("unroll")                                                       \
        for (int ot = 0; ot < 4; ++ot) acc[ot] = (f32x4){0.f, 0.f, 0.f, 0.f};   \
        _Pragma("unroll")                                                       \
        for (int kc = 0; kc < 4; ++kc) {                                        \
            int g0 = kc * 8 + q * 2;    /* logical 4-float granule */           \
            float4 e0 = *(const float4*)(lbase + r16 * 128 + ((g0 ^ (r16 & 7)) * 4));        \
            float4 e1 = *(const float4*)(lbase + r16 * 128 + (((g0 + 1) ^ (r16 & 7)) * 4));  \
            v8h eh;                                                             \
            eh[0] = (_Float16)e0.x; eh[1] = (_Float16)e0.y;                     \
            eh[2] = (_Float16)e0.z; eh[3] = (_Float16)e0.w;                     \
            eh[4] = (_Float16)e1.x; eh[5] = (_Float16)e1.y;                     \
            eh[6] = (_Float16)e1.z; eh[7] = (_Float16)e1.w;                     \
            _Pragma("unroll")                                                   \
            for (int ot = 0; ot < 4; ++ot)                                      \
                acc[ot] = __builtin_amdgcn_mfma_f32_16x16x32_f16(bw[kc][ot], eh, acc[ot], 0, 0, 0); \
        }                                                                       \
        float* dst_row = out + (orow_base + (tile) * 16 + r16) * OO + q * 4;    \
        _Pragma("unroll")                                                       \
        for (int ot = 0; ot < 4; ++ot) {                                        \
            float4 v;                                                           \
            v.x = acc[ot][0]; v.y = acc[ot][1];                                 \
            v.z = acc[ot][2]; v.w = acc[ot][3];                                 \
            *(float4*)(dst_row + ot * 16) = v;                                  \
        }                                                                       \
    }

    STAGE(0, 0);

#pragma unroll 1
    for (int i = 0; i < 7; ++i) {
        STAGE(i + 1, (i + 1) & 1);
        __builtin_amdgcn_sched_barrier(0);
        asm volatile("s_waitcnt vmcnt(8)" ::: "memory");   // tile i drained; i+1 in flight
        __builtin_amdgcn_sched_barrier(0);
        CONSUME(i, i & 1);
    }
    __builtin_amdgcn_sched_barrier(0);
    asm volatile("s_waitcnt vmcnt(4)" ::: "memory");       // loads(7) drained; stores(6) may fly
    __builtin_amdgcn_sched_barrier(0);
    CONSUME(7, 1);
#undef STAGE
#undef CONSUME
}

extern "C" void kernel_launch(void* const* d_in, const int* in_sizes, int n_in,
                              void* d_out, int out_size, void* d_ws, size_t ws_size,
                              hipStream_t stream) {
    const float* eeg   = (const float*)d_in[0];   // [B,T,C]
    const float* pos   = (const float*)d_in[1];   // [B,C,2]
    const float* heads = (const float*)d_in[2];   // [O,D]
    float* out = (float*)d_out;                   // [B,T,O]

    char* ws = (char*)d_ws;
    float* Ht     = (float*)ws;                       // 288*64*4    = 73728 B
    float* w      = (float*)(ws + 73728);             // 32*64*128*4 = 1048576 B
    uint4* fragH  = (uint4*)(ws + 73728 + 1048576);   // 32*4*4*64*16 = 524288 B

    k0_transpose_heads<<<(OO * DD + 255) / 256, 256, 0, stream>>>(heads, Ht);
    k1_weights<<<dim3(BB, 4), 256, 0, stream>>>(pos, Ht, w);
    k1b_frag<<<dim3(BB, 4), 256, 0, stream>>>(w, fragH);
    k2_mfma<<<512, 256, 0, stream>>>(eeg, fragH, out);
}

// Round 11
// 57.219 us; speedup vs baseline: 1.2497x; 1.2175x over previous
//
#include <hip/hip_runtime.h>
#include <math.h>

#define BB 32
#define TT 8192
#define CCH 128
#define OO 64
#define DD 288
#define NFREQ 12
#define NIJ 144

typedef _Float16 v8h __attribute__((ext_vector_type(8)));
typedef float f32x4 __attribute__((ext_vector_type(4)));

// ---------------- K1f: fourier emb + scores + softmax -> fragH, fused ----------------
// Replaces k0+k1+k1b (serial-launch overhead was ~7us of a 70us total).
// grid (32 b, 4 oy); 256 threads. Block owns o-range [oy*16, +16).
// - heads read DIRECTLY via wave-uniform scalar loads (hh readfirstlane'd,
//   cc+ijl loop-uniform) -> s_load; Ht transpose kernel unnecessary.
// - after softmax, thread (o16, part) holds w[obase+o16][part*8..+8] = exactly
//   the 8 halves of fragment (kc=part>>2, ot=oy, lane=(part&3)*16+o16) -> emit
//   fragH here; k1b unnecessary.
#define IJ_CHUNK 36
#define EMB_LD 129

__global__ __launch_bounds__(256) void k1f_frag(const float* __restrict__ pos,
                                                const float* __restrict__ heads,
                                                uint4* __restrict__ fragH) {
    __shared__ float smem[2 * IJ_CHUNK * EMB_LD];   // 9288 floats = 37 KB
    float* cos_s = smem;
    float* sin_s = smem + IJ_CHUNK * EMB_LD;

    const int b = blockIdx.x;
    const int oy = blockIdx.y;            // == ot of the fragment
    const int obase = oy * 16;
    const int tid = threadIdx.x;
    const int c = tid & 127;
    const int hh = __builtin_amdgcn_readfirstlane(tid >> 7);  // wave-uniform

    const float* posb = pos + b * CCH * 2;
    const float S = 4.487989505128276f;  // 2*pi/1.4

    float accs[8];
#pragma unroll
    for (int k = 0; k < 8; ++k) accs[k] = 0.f;

#pragma unroll 1
    for (int cc = 0; cc < NIJ; cc += IJ_CHUNK) {
#pragma unroll 1
        for (int it = 0; it < (IJ_CHUNK * CCH) / 256; ++it) {
            int idx = it * 256 + tid;
            int ec = idx & 127;
            int ijl = idx >> 7;
            int ij = cc + ijl;
            int i = ij / NFREQ;
            int j = ij - i * NFREQ;
            float px = posb[2 * ec] + 0.2f;
            float py = posb[2 * ec + 1] + 0.2f;
            float ang = px * (S * (float)i) + py * (S * (float)j);
            float sv, cv;
            __sincosf(ang, &sv, &cv);
            cos_s[ijl * EMB_LD + ec] = cv;
            sin_s[ijl * EMB_LD + ec] = sv;
        }
        __syncthreads();
#pragma unroll 4
        for (int ijl = 0; ijl < IJ_CHUNK; ++ijl) {
            float cv = cos_s[ijl * EMB_LD + c];
            float sv = sin_s[ijl * EMB_LD + c];
            // heads[o][d]: cos part d = ij, sin part d = 144 + ij. Row o = obase+hh*8+k.
            const float* hrow = heads + (size_t)(obase + hh * 8) * DD + (cc + ijl);
#pragma unroll
            for (int k = 0; k < 8; ++k) {
                accs[k] = fmaf(cv, hrow[k * DD], fmaf(sv, hrow[k * DD + NIJ], accs[k]));
            }
        }
        __syncthreads();
    }

    // scores -> LDS [16][129]
    float* sc = smem;
#pragma unroll
    for (int k = 0; k < 8; ++k) {
        sc[(hh * 8 + k) * EMB_LD + c] = accs[k];
    }
    __syncthreads();

    // parallel softmax: o16 = tid>>4 owns one o-row; part = tid&15 owns 8 channels
    float* red  = smem + 16 * EMB_LD;        // 256 floats
    float* red2 = red + 256;                 // 256 floats
    const int o16 = tid >> 4;
    const int part = tid & 15;
    const float* srow = sc + o16 * EMB_LD + part * 8;

    float m = -1e30f;
#pragma unroll
    for (int j = 0; j < 8; ++j) m = fmaxf(m, srow[j]);
    red[o16 * 16 + part] = m;
    __syncthreads();
    float M = red[o16 * 16];
#pragma unroll
    for (int p = 1; p < 16; ++p) M = fmaxf(M, red[o16 * 16 + p]);

    float ev[8];
    float s = 0.f;
#pragma unroll
    for (int j = 0; j < 8; ++j) { ev[j] = __expf(srow[j] - M); s += ev[j]; }
    red2[o16 * 16 + part] = s;
    __syncthreads();
    float Sum = 0.f;
#pragma unroll
    for (int p = 0; p < 16; ++p) Sum += red2[o16 * 16 + p];
    float inv = 1.f / Sum;

    // ---- fragment emission (was k1b) ----
    // thread (o16, part) holds w[obase+o16][part*8 .. +8) = halves (part*8..+8)
    // of the A-fragment: kc = part>>2, slot q = part&3, lane = q*16 + o16.
    v8h h;
#pragma unroll
    for (int j = 0; j < 8; ++j) h[j] = (_Float16)(ev[j] * inv);
    union { uint4 u; v8h v; } u;
    u.v = h;
    const int kc = part >> 2;
    const int lane = (part & 3) * 16 + o16;
    fragH[((b * 4 + kc) * 4 + oy) * 64 + lane] = u.u;
}

// ---------------- K2: out[b,t,o] = sum_c eeg[b,t,c] * w[b,o,c] via fp16 MFMA ----
// R6 structure (best measured): 256 thr = 4 waves; wave owns 64 t-rows (4 tiles
// of 16), direct global loads, no LDS. mfma(A=w_frag, B=eeg_frag):
// D[row=o_local=kq*4+reg][col=t_local=r16] -> float4 stores.
// RULE #20: every acc[][] loop fully unrolled.
__global__ __launch_bounds__(256) void k2_mfma(const float* __restrict__ eeg,
                                               const uint4* __restrict__ fragH,
                                               float* __restrict__ out) {
    const int b = blockIdx.y;
    const int t0 = blockIdx.x * 256;
    const int lane = threadIdx.x & 63;
    const int wv = __builtin_amdgcn_readfirstlane(threadIdx.x >> 6);
    const int r16 = lane & 15;
    const int kq = lane >> 4;

    const float* ebase = eeg + ((size_t)b * TT + t0 + wv * 64) * CCH;

    f32x4 acc[4][4];
#pragma unroll
    for (int tt = 0; tt < 4; ++tt)
#pragma unroll
        for (int ot = 0; ot < 4; ++ot)
            acc[tt][ot] = (f32x4){0.f, 0.f, 0.f, 0.f};

#pragma unroll 1
    for (int kc = 0; kc < 4; ++kc) {
        const uint4* fh = fragH + (size_t)((b * 4 + kc) * 4) * 64 + lane;
        v8h bw[4];
#pragma unroll
        for (int ot = 0; ot < 4; ++ot) {
            union { uint4 u; v8h v; } u;
            u.u = fh[ot * 64];
            bw[ot] = u.v;
        }
#pragma unroll
        for (int tt = 0; tt < 4; ++tt) {
            const float* ap = ebase + (size_t)(tt * 16 + r16) * CCH + kc * 32 + kq * 8;
            float4 v0 = *(const float4*)ap;
            float4 v1 = *(const float4*)(ap + 4);
            v8h eh;
            eh[0] = (_Float16)v0.x; eh[1] = (_Float16)v0.y;
            eh[2] = (_Float16)v0.z; eh[3] = (_Float16)v0.w;
            eh[4] = (_Float16)v1.x; eh[5] = (_Float16)v1.y;
            eh[6] = (_Float16)v1.z; eh[7] = (_Float16)v1.w;
#pragma unroll
            for (int ot = 0; ot < 4; ++ot) {
                acc[tt][ot] = __builtin_amdgcn_mfma_f32_16x16x32_f16(bw[ot], eh, acc[tt][ot], 0, 0, 0);
            }
        }
    }

    // epilogue: lane holds D[o_local = kq*4 + reg][t_local = r16] per (tt,ot)
    const size_t orow0 = (size_t)b * TT + t0 + wv * 64;
#pragma unroll
    for (int tt = 0; tt < 4; ++tt) {
        float* dst_row = out + (orow0 + tt * 16 + r16) * OO + kq * 4;
#pragma unroll
        for (int ot = 0; ot < 4; ++ot) {
            float4 v;
            v.x = acc[tt][ot][0];
            v.y = acc[tt][ot][1];
            v.z = acc[tt][ot][2];
            v.w = acc[tt][ot][3];
            *(float4*)(dst_row + ot * 16) = v;
        }
    }
}

extern "C" void kernel_launch(void* const* d_in, const int* in_sizes, int n_in,
                              void* d_out, int out_size, void* d_ws, size_t ws_size,
                              hipStream_t stream) {
    const float* eeg   = (const float*)d_in[0];   // [B,T,C]
    const float* pos   = (const float*)d_in[1];   // [B,C,2]
    const float* heads = (const float*)d_in[2];   // [O,D]
    float* out = (float*)d_out;                   // [B,T,O]

    uint4* fragH = (uint4*)d_ws;                  // 32*4*4*64*16 = 524288 B

    k1f_frag<<<dim3(BB, 4), 256, 0, stream>>>(pos, heads, fragH);
    k2_mfma<<<dim3(TT / 256, BB), 256, 0, stream>>>(eeg, fragH, out);
}